// Round 1
// baseline (500.845 us; speedup 1.0000x reference)
//
#include <hip/hip_runtime.h>
#include <hip/hip_bf16.h>
#include <stdint.h>

// ---------------------------------------------------------------------------
// SelfAttention: B=4 S=2048 D=1024 H=16 HD=64. I/O dtype: FLOAT32.
//   0) cvt: x, Wq, Wk, Wv, Wo  f32 -> bf16
//   1) gemm_qkv (fused, 1536 blocks = 4/CU); V stored CHUNK-MAJOR
//      Vt[BH][S/64][HD][64]  (8KB contiguous tiles per 64-key chunk)
//   2) attn: transposed-S flash, no online max. R9: NO LDS / NO BARRIERS —
//      K/V fragments read directly from global (per-head K+V = 512KB, fully
//      L2-resident; guide m169: staging L2-fit data is pure overhead). 8-wave
//      blocks (256 q rows) halve redundant K/V reads; setprio(1) around
//      compute. Removes the per-chunk vmcnt(0)+barrier drain that capped
//      MfmaUtil at 33%.
//   3) gemm_o: 128x128 tile (R6 version)
// ---------------------------------------------------------------------------

typedef __bf16 bf16;
typedef __bf16 bf16x8 __attribute__((ext_vector_type(8)));
typedef __bf16 bf16x4 __attribute__((ext_vector_type(4)));
typedef float  f32x4  __attribute__((ext_vector_type(4)));

#define MFMA_BF16(A, B, C) __builtin_amdgcn_mfma_f32_16x16x32_bf16(A, B, C, 0, 0, 0)
#define EXP2F(x) __builtin_amdgcn_exp2f(x)

#define ASYNC_CP16(DST_LDS, SRC_G)                                            \
  __builtin_amdgcn_global_load_lds(                                           \
      (__attribute__((address_space(1))) void*)(SRC_G),                       \
      (__attribute__((address_space(3))) void*)(DST_LDS), 16, 0, 0)

// ---------------------------------------------------------------------------
__global__ __launch_bounds__(256) void cvt5(
    const float* __restrict__ s0, bf16* __restrict__ d0, int n0,
    const float* __restrict__ s1, bf16* __restrict__ d1, int n1,
    const float* __restrict__ s2, bf16* __restrict__ d2, int n2,
    const float* __restrict__ s3, bf16* __restrict__ d3, int n3,
    const float* __restrict__ s4, bf16* __restrict__ d4, int n4)
{
  const float* s; bf16* d; int n;
  switch (blockIdx.y) {
    case 0: s = s0; d = d0; n = n0; break;
    case 1: s = s1; d = d1; n = n1; break;
    case 2: s = s2; d = d2; n = n2; break;
    case 3: s = s3; d = d3; n = n3; break;
    default: s = s4; d = d4; n = n4; break;
  }
  const int stride = gridDim.x * blockDim.x * 4;
  for (int i = (blockIdx.x * blockDim.x + threadIdx.x) * 4; i < n; i += stride) {
    const float4 v = *(const float4*)(s + i);
    bf16x4 o;
    o[0] = (bf16)v.x; o[1] = (bf16)v.y; o[2] = (bf16)v.z; o[3] = (bf16)v.w;
    *(bf16x4*)(d + i) = o;
  }
}

// ---------------------------------------------------------------------------
// Fused QKV GEMM. grid (24,64): blockIdx.x>>3 selects {Q,K,V}; &7 is nbase.
// V stored chunk-major: Vt[bh][s>>6][hd][s&63].
// ---------------------------------------------------------------------------
__global__ __launch_bounds__(256, 4) void gemm_qkv(
    const bf16* __restrict__ X,
    const bf16* __restrict__ Wq, const bf16* __restrict__ Wk,
    const bf16* __restrict__ Wv,
    const float* __restrict__ bq, const float* __restrict__ bk,
    const float* __restrict__ bv,
    bf16* __restrict__ Qo, bf16* __restrict__ Ko, bf16* __restrict__ Vo,
    float qscale)
{
  constexpr int N = 1024, K = 1024;
  __shared__ alignas(16) bf16 As[8192];
  __shared__ alignas(16) bf16 Bs[8192];

  const int sel = blockIdx.x >> 3;          // 0=Q 1=K 2=V
  const bf16*  W    = (sel == 0) ? Wq : (sel == 1) ? Wk : Wv;
  const float* bias = (sel == 0) ? bq : (sel == 1) ? bk : bv;
  bf16*        Y    = (sel == 0) ? Qo : (sel == 1) ? Ko : Vo;
  const float scale = (sel == 0) ? qscale : 1.0f;

  const int tid  = threadIdx.x;
  const int lane = tid & 63;
  const int wv   = tid >> 6;
  const int l15  = lane & 15;
  const int quad = lane >> 4;
  const int wm   = (wv >> 1) * 64;
  const int wn   = (wv & 1) * 64;
  const int nbase = (blockIdx.x & 7) * 128;
  const int mbase = blockIdx.y * 128;

  f32x4 acc[4][4];
  #pragma unroll
  for (int i = 0; i < 4; ++i)
    #pragma unroll
    for (int j = 0; j < 4; ++j)
      acc[i][j] = (f32x4){0.f, 0.f, 0.f, 0.f};

  const int r8 = lane >> 3;
  const int oc = (lane & 7) ^ r8;
  const size_t lrowA = (size_t)(mbase + wv * 32 + r8);
  const size_t lrowB = (size_t)(nbase + wv * 32 + r8);

  for (int kb = 0; kb < K; kb += 64) {
    #pragma unroll
    for (int c = 0; c < 4; ++c) {
      ASYNC_CP16(As + (wv * 32 + c * 8) * 64, X + (lrowA + c * 8) * K + kb + oc * 8);
      ASYNC_CP16(Bs + (wv * 32 + c * 8) * 64, W + (lrowB + c * 8) * K + kb + oc * 8);
    }
    __syncthreads();
    #pragma unroll
    for (int ks = 0; ks < 2; ++ks) {
      bf16x8 af[4], bfr[4];
      #pragma unroll
      for (int t = 0; t < 4; ++t) {
        const int ma = wm + t * 16 + l15;
        af[t]  = *(const bf16x8*)(As + (ma * 8 + ((ks * 4 + quad) ^ (ma & 7))) * 8);
        const int nb = wn + t * 16 + l15;
        bfr[t] = *(const bf16x8*)(Bs + (nb * 8 + ((ks * 4 + quad) ^ (nb & 7))) * 8);
      }
      #pragma unroll
      for (int i = 0; i < 4; ++i)
        #pragma unroll
        for (int j = 0; j < 4; ++j)
          acc[i][j] = MFMA_BF16(af[i], bfr[j], acc[i][j]);
    }
    __syncthreads();
  }

  #pragma unroll
  for (int i = 0; i < 4; ++i) {
    const int row0 = mbase + wm + i * 16 + quad * 4;
    #pragma unroll
    for (int j = 0; j < 4; ++j) {
      const int col = nbase + wn + j * 16 + l15;
      const float bv2 = bias[col];
      #pragma unroll
      for (int r = 0; r < 4; ++r) {
        const float v = (acc[i][j][r] + bv2) * scale;
        const int row = row0 + r;
        if (sel != 2) {
          Y[(size_t)row * N + col] = (bf16)v;
        } else {
          const int bb = row >> 11, s  = row & 2047;
          const int hh = col >> 6,  hd = col & 63;
          // chunk-major: [bh][s>>6][hd][s&63]
          Y[(size_t)(bb * 16 + hh) * (2048 * 64) + (size_t)(s >> 6) * 4096 +
            hd * 64 + (s & 63)] = (bf16)v;
        }
      }
    }
  }
}

// ---------------------------------------------------------------------------
// O-projection GEMM (f32 out), 128x128 tile, grid (8,64) — R6 version.
// ---------------------------------------------------------------------------
__global__ __launch_bounds__(256) void gemm_o(
    const bf16* __restrict__ X, const bf16* __restrict__ W,
    const float* __restrict__ bias, float* __restrict__ Yf)
{
  constexpr int N = 1024, K = 1024;
  __shared__ alignas(16) bf16 As[8192];
  __shared__ alignas(16) bf16 Bs[8192];

  const int tid  = threadIdx.x;
  const int lane = tid & 63;
  const int wv   = tid >> 6;
  const int l15  = lane & 15;
  const int quad = lane >> 4;
  const int wm   = (wv >> 1) * 64;
  const int wn   = (wv & 1) * 64;
  const int nbase = blockIdx.x * 128;
  const int mbase = blockIdx.y * 128;

  f32x4 acc[4][4];
  #pragma unroll
  for (int i = 0; i < 4; ++i)
    #pragma unroll
    for (int j = 0; j < 4; ++j)
      acc[i][j] = (f32x4){0.f, 0.f, 0.f, 0.f};

  const int r8 = lane >> 3;
  const int oc = (lane & 7) ^ r8;
  const size_t lrowA = (size_t)(mbase + wv * 32 + r8);
  const size_t lrowB = (size_t)(nbase + wv * 32 + r8);

  for (int kb = 0; kb < K; kb += 64) {
    #pragma unroll
    for (int c = 0; c < 4; ++c) {
      ASYNC_CP16(As + (wv * 32 + c * 8) * 64, X + (lrowA + c * 8) * K + kb + oc * 8);
      ASYNC_CP16(Bs + (wv * 32 + c * 8) * 64, W + (lrowB + c * 8) * K + kb + oc * 8);
    }
    __syncthreads();
    #pragma unroll
    for (int ks = 0; ks < 2; ++ks) {
      bf16x8 af[4], bfr[4];
      #pragma unroll
      for (int t = 0; t < 4; ++t) {
        const int ma = wm + t * 16 + l15;
        af[t]  = *(const bf16x8*)(As + (ma * 8 + ((ks * 4 + quad) ^ (ma & 7))) * 8);
        const int nb = wn + t * 16 + l15;
        bfr[t] = *(const bf16x8*)(Bs + (nb * 8 + ((ks * 4 + quad) ^ (nb & 7))) * 8);
      }
      #pragma unroll
      for (int i = 0; i < 4; ++i)
        #pragma unroll
        for (int j = 0; j < 4; ++j)
          acc[i][j] = MFMA_BF16(af[i], bfr[j], acc[i][j]);
    }
    __syncthreads();
  }

  #pragma unroll
  for (int i = 0; i < 4; ++i) {
    const int row0 = mbase + wm + i * 16 + quad * 4;
    #pragma unroll
    for (int j = 0; j < 4; ++j) {
      const int col = nbase + wn + j * 16 + l15;
      const float bv2 = bias[col];
      #pragma unroll
      for (int r = 0; r < 4; ++r)
        Yf[(size_t)(row0 + r) * N + col] = acc[i][j][r] + bv2;
    }
  }
}

// ---------------------------------------------------------------------------
// Flash attention, transposed-S, no online max. R9: NO LDS, NO BARRIERS.
// Each wave owns 32 q rows; K/V fragments loaded straight from global
// (L1/L2-hit: per-head K+V = 512KB << 4MB L2/XCD; all 8 waves of a block
// read the same chunk lines -> L1 temporal reuse).
// Fragment/key mapping identical to the verified R4/R8 layout:
//   A-row l15 of QK^T holds key  kla(l15) + 4*(kt&1) + 32*(kt>>1),
//   kla = 8*(l15>>2) + (l15&3); kf0 = hd[ q0*8 .. +7 ], kf1 = +32.
//   V fragment: A-row l15 = hd ht*16+l15, k = keys q0*8..+7 (vf0), +32 (vf1).
// ---------------------------------------------------------------------------
__global__ __launch_bounds__(512, 4) void attn(
    const bf16* __restrict__ Qb, const bf16* __restrict__ Kb,
    const bf16* __restrict__ Vt, bf16* __restrict__ Ob)
{
  constexpr int S = 2048, D = 1024;

  const int tid  = threadIdx.x;
  const int lane = tid & 63;
  const int wv   = tid >> 6;        // 0..7
  const int l15  = lane & 15;
  const int q0   = lane >> 4;
  const int b = blockIdx.z, h = blockIdx.y;
  const int qblk = blockIdx.x * 256 + wv * 32;

  bf16x8 qf[2][2];
  #pragma unroll
  for (int qt = 0; qt < 2; ++qt)
    #pragma unroll
    for (int dh = 0; dh < 2; ++dh)
      qf[qt][dh] = *(const bf16x8*)(
          Qb + (size_t)(b * S + qblk + qt * 16 + l15) * D + h * 64 + dh * 32 + q0 * 8);

  float lrun[2] = {0.f, 0.f};
  f32x4 o[4][2];   // o[ht][qt]
  #pragma unroll
  for (int ht = 0; ht < 4; ++ht)
    #pragma unroll
    for (int qt = 0; qt < 2; ++qt)
      o[ht][qt] = (f32x4){0.f, 0.f, 0.f, 0.f};

  const int kla = 8 * (l15 >> 2) + (l15 & 3);   // permuted key row for this lane
  const bf16* kbase = Kb + (size_t)(b * S) * D + h * 64 + q0 * 8;
  const bf16* vbase = Vt + (size_t)(b * 16 + h) * (2048 * 64) + q0 * 8;

  for (int kc = 0; kc < S; kc += 64) {
    // ---- issue all 16 fragment loads for this chunk (no LDS round-trip) ----
    bf16x8 kf[4][2];
    #pragma unroll
    for (int kt = 0; kt < 4; ++kt) {
      const bf16* kp =
          kbase + (size_t)(kc + kla + 4 * (kt & 1) + 32 * (kt >> 1)) * D;
      kf[kt][0] = *(const bf16x8*)(kp);
      kf[kt][1] = *(const bf16x8*)(kp + 32);
    }
    bf16x8 vf[4][2];
    const bf16* vp0 = vbase + (size_t)(kc >> 6) * 4096;
    #pragma unroll
    for (int ht = 0; ht < 4; ++ht) {
      const bf16* vp = vp0 + (ht * 16 + l15) * 64;
      vf[ht][0] = *(const bf16x8*)(vp);
      vf[ht][1] = *(const bf16x8*)(vp + 32);
    }

    __builtin_amdgcn_s_setprio(1);

    // ---- QK^T + exp2 + pack, per key group (keeps sc liveness small) ----
    bf16x8 pb[2][2];
    #pragma unroll
    for (int kt = 0; kt < 4; ++kt) {
      #pragma unroll
      for (int qt = 0; qt < 2; ++qt) {
        f32x4 s = MFMA_BF16(kf[kt][0], qf[qt][0], ((f32x4){0.f, 0.f, 0.f, 0.f}));
        s = MFMA_BF16(kf[kt][1], qf[qt][1], s);
        float ps = 0.f;
        #pragma unroll
        for (int r = 0; r < 4; ++r) {
          const float p = EXP2F(s[r]);
          ps += p;
          pb[qt][kt >> 1][(kt & 1) * 4 + r] = (bf16)p;
        }
        lrun[qt] += ps;
      }
    }

    // ---- PV ----
    #pragma unroll
    for (int ht = 0; ht < 4; ++ht) {
      #pragma unroll
      for (int qt = 0; qt < 2; ++qt) {
        o[ht][qt] = MFMA_BF16(vf[ht][0], pb[qt][0], o[ht][qt]);
        o[ht][qt] = MFMA_BF16(vf[ht][1], pb[qt][1], o[ht][qt]);
      }
    }

    __builtin_amdgcn_s_setprio(0);
  }

  #pragma unroll
  for (int qt = 0; qt < 2; ++qt) {
    float l = lrun[qt];
    l += __shfl_xor(l, 16, 64);
    l += __shfl_xor(l, 32, 64);
    const float inv = 1.0f / l;
    bf16* orow = Ob + (size_t)(b * S + qblk + qt * 16 + l15) * D + h * 64 + q0 * 4;
    #pragma unroll
    for (int ht = 0; ht < 4; ++ht) {
      bf16x4 w;
      w[0] = (bf16)(o[ht][qt][0] * inv);
      w[1] = (bf16)(o[ht][qt][1] * inv);
      w[2] = (bf16)(o[ht][qt][2] * inv);
      w[3] = (bf16)(o[ht][qt][3] * inv);
      *(bf16x4*)(orow + ht * 16) = w;
    }
  }
}

// ---------------------------------------------------------------------------
extern "C" void kernel_launch(void* const* d_in, const int* in_sizes, int n_in,
                              void* d_out, int out_size, void* d_ws, size_t ws_size,
                              hipStream_t stream)
{
  const float* x  = (const float*)d_in[0];
  const float* Wq = (const float*)d_in[1];
  const float* bq = (const float*)d_in[2];
  const float* Wk = (const float*)d_in[3];
  const float* bk = (const float*)d_in[4];
  const float* Wv = (const float*)d_in[5];
  const float* bv = (const float*)d_in[6];
  const float* Wo = (const float*)d_in[7];
  const float* bo = (const float*)d_in[8];
  float* out = (float*)d_out;

  const size_t NX = (size_t)8192 * 1024;
  const size_t NW = (size_t)1024 * 1024;

  bf16* xb  = (bf16*)d_ws;
  bf16* Wqb = xb  + NX;
  bf16* Wkb = Wqb + NW;
  bf16* Wvb = Wkb + NW;
  bf16* Wob = Wvb + NW;
  bf16* Qb  = Wob + NW;
  bf16* Kb  = Qb  + NX;
  bf16* Vt  = Kb  + NX;   // chunk-major [BH][S/64][HD][64]
  bf16* Ctx = Vt  + NX;

  const float QSCALE = 0.18033688011112042f;  // 0.125 * log2(e)

  dim3 bc(256, 1, 1);
  hipLaunchKernelGGL(cvt5, dim3(1024, 5, 1), bc, 0, stream,
                     x, xb, (int)NX, Wq, Wqb, (int)NW, Wk, Wkb, (int)NW,
                     Wv, Wvb, (int)NW, Wo, Wob, (int)NW);

  hipLaunchKernelGGL(gemm_qkv, dim3(24, 64, 1), bc, 0, stream,
                     xb, Wqb, Wkb, Wvb, bq, bk, bv, Qb, Kb, Vt, QSCALE);

  hipLaunchKernelGGL(attn, dim3(8, 16, 4), dim3(512, 1, 1), 0, stream,
                     Qb, Kb, Vt, Ctx);

  hipLaunchKernelGGL(gemm_o, dim3(8, 64, 1), bc, 0, stream, Ctx, Wob, bo, out);
}